// Round 7
// baseline (409.630 us; speedup 1.0000x reference)
//
#include <hip/hip_runtime.h>
#include <hip/hip_bf16.h>

#define IN_DIM 128
#define HC 256
#define HEADS 8
#define OUT_DIM 32
#define NEG_SLOPE 0.2f
#define ELL_CAP 64           // Poisson(16) degrees: P(deg>63) ~ 1e-19 per node

typedef unsigned short ushort_t;
typedef unsigned int uint_t;
typedef __attribute__((ext_vector_type(8))) short bf16x8;
typedef __attribute__((ext_vector_type(4))) float floatx4;

__device__ inline float bf2fu(uint_t u) {     // low 16 bits -> f32
    return __uint_as_float(u << 16);
}
// packed 2xf32 -> 2xbf16 (v_cvt_pk_bf16_f32), RNE
__device__ inline uint_t pkbf(float a, float b) {
    __hip_bfloat162 t = __float22bfloat162_rn(make_float2(a, b));
    union { __hip_bfloat162 h; uint_t u; } c;
    c.h = t;
    return c.u;
}
// accumulate 16 bf16 dims (2x uint4) scaled by p into acc[0..15]
__device__ inline void fmab(uint4 a, uint4 b, float p, float* acc) {
    acc[0]  += p * bf2fu(a.x & 0xffffu);  acc[1]  += p * bf2fu(a.x >> 16);
    acc[2]  += p * bf2fu(a.y & 0xffffu);  acc[3]  += p * bf2fu(a.y >> 16);
    acc[4]  += p * bf2fu(a.z & 0xffffu);  acc[5]  += p * bf2fu(a.z >> 16);
    acc[6]  += p * bf2fu(a.w & 0xffffu);  acc[7]  += p * bf2fu(a.w >> 16);
    acc[8]  += p * bf2fu(b.x & 0xffffu);  acc[9]  += p * bf2fu(b.x >> 16);
    acc[10] += p * bf2fu(b.y & 0xffffu);  acc[11] += p * bf2fu(b.y >> 16);
    acc[12] += p * bf2fu(b.z & 0xffffu);  acc[13] += p * bf2fu(b.z >> 16);
    acc[14] += p * bf2fu(b.w & 0xffffu);  acc[15] += p * bf2fu(b.w >> 16);
}

// ---------------- K1: [Wstack writer | pack x->bf16 + attention dots | ELL build] ----------------
// Wstack: projection weights in MFMA B-frag layout: Wstack[c*1024 + h*128 + d] = W[d][h*32+c].
// pack: xb = bf16(x) row-major (gather table, 12.8 MB), a_src8/a_dst8[n][8] = x . (W @ att).
// build: R0-proven ELL bucket build (row-major ell[dst*64+slot]).
__global__ __launch_bounds__(256) void prep_pack_build(
    const float* __restrict__ x,
    const float* __restrict__ W,
    const float* __restrict__ att_s,
    const float* __restrict__ att_d,
    ushort_t* __restrict__ Wstack,
    ushort_t* __restrict__ xb,
    float* __restrict__ a_src8,
    float* __restrict__ a_dst8,
    const int* __restrict__ esrc,
    const int* __restrict__ edst,
    int* __restrict__ deg,
    ushort_t* __restrict__ ell,
    int N, int E, int npack)
{
    const int bid = blockIdx.x;
    const int tid = threadIdx.x;

    if (bid < 16) {
        // ---- Wstack: 4096 threads x 8 consecutive elements of [32][1024] ----
        int t = bid * 256 + tid;
        int c = t >> 7;                   // t*8 / 1024
        int k0 = (t * 8) & 1023;
        int h = k0 >> 7;
        int d0 = k0 & 127;
        float v[8];
#pragma unroll
        for (int j = 0; j < 8; j++) v[j] = W[(size_t)(d0 + j) * HC + h * 32 + c];
        uint4 pk;
        pk.x = pkbf(v[0], v[1]); pk.y = pkbf(v[2], v[3]);
        pk.z = pkbf(v[4], v[5]); pk.w = pkbf(v[6], v[7]);
        *(uint4*)&Wstack[(size_t)t * 8] = pk;
        return;
    }

    if (bid < 16 + npack) {
        // ---- pack block: 64 x-rows ----
        __shared__ float was[128 * 9];    // wa[k][h], +1 pad breaks stride-32 conflicts
        __shared__ float wad[128 * 9];
#pragma unroll
        for (int q = 0; q < 8; q++) {
            int idx = q * 256 + tid;      // 0..2047 = (k, h, src/dst)
            int k = idx >> 4;
            int rem = idx & 15;
            int h = rem >> 1;
            const float* att = (rem & 1) ? att_d : att_s;
            float s = 0.f;
#pragma unroll
            for (int c = 0; c < 32; c++) s += W[(size_t)k * HC + h * 32 + c] * att[h * 32 + c];
            if (rem & 1) wad[k * 9 + h] = s; else was[k * 9 + h] = s;
        }
        __syncthreads();

        const int base = (bid - 16) * 64;
        const int q = tid & 31;           // dim quad: dims q*4..q*4+3
#pragma unroll
        for (int iter = 0; iter < 8; iter++) {
            int r = iter * 8 + (tid >> 5);
            int gr = base + r;
            if (gr >= N) continue;
            float4 xv = *(const float4*)&x[(size_t)gr * IN_DIM + q * 4];
            uint2 pk;
            pk.x = pkbf(xv.x, xv.y); pk.y = pkbf(xv.z, xv.w);
            *(uint2*)&xb[(size_t)gr * IN_DIM + q * 4] = pk;
            float ps[8] = {0,0,0,0,0,0,0,0}, pd[8] = {0,0,0,0,0,0,0,0};
#pragma unroll
            for (int i = 0; i < 4; i++) {
                int k = q * 4 + i;
                float xe = (i == 0) ? xv.x : (i == 1) ? xv.y : (i == 2) ? xv.z : xv.w;
#pragma unroll
                for (int hh = 0; hh < 8; hh++) {
                    ps[hh] += xe * was[k * 9 + hh];
                    pd[hh] += xe * wad[k * 9 + hh];
                }
            }
#pragma unroll
            for (int off = 1; off < 32; off <<= 1) {
#pragma unroll
                for (int hh = 0; hh < 8; hh++) {
                    ps[hh] += __shfl_xor(ps[hh], off, 64);
                    pd[hh] += __shfl_xor(pd[hh], off, 64);
                }
            }
            if (q == 0) {
                *(float4*)&a_src8[(size_t)gr * 8]     = make_float4(ps[0], ps[1], ps[2], ps[3]);
                *(float4*)&a_src8[(size_t)gr * 8 + 4] = make_float4(ps[4], ps[5], ps[6], ps[7]);
                *(float4*)&a_dst8[(size_t)gr * 8]     = make_float4(pd[0], pd[1], pd[2], pd[3]);
                *(float4*)&a_dst8[(size_t)gr * 8 + 4] = make_float4(pd[4], pd[5], pd[6], pd[7]);
            }
        }
        return;
    }

    // ---- ELL build (R0 pattern) ----
    int i = (bid - 16 - npack) * 256 + tid;
    int baseE = i * 4;
    if (baseE + 3 < E) {
        int4 d = *(const int4*)&edst[baseE];
        int4 s = *(const int4*)&esrc[baseE];
        int r0 = atomicAdd(&deg[d.x], 1);
        int r1 = atomicAdd(&deg[d.y], 1);
        int r2 = atomicAdd(&deg[d.z], 1);
        int r3 = atomicAdd(&deg[d.w], 1);
        if (r0 < ELL_CAP) ell[d.x * ELL_CAP + r0] = (ushort_t)s.x;
        if (r1 < ELL_CAP) ell[d.y * ELL_CAP + r1] = (ushort_t)s.y;
        if (r2 < ELL_CAP) ell[d.z * ELL_CAP + r2] = (ushort_t)s.z;
        if (r3 < ELL_CAP) ell[d.w * ELL_CAP + r3] = (ushort_t)s.w;
    } else {
        for (int j = baseE; j < E; j++) {
            int r = atomicAdd(&deg[edst[j]], 1);
            if (r < ELL_CAP) ell[edst[j] * ELL_CAP + r] = (ushort_t)esrc[j];
        }
    }
}

// ---------------- K2: x-space aggregate + fused MFMA projection ----------------
// Block = 16 nodes (4 waves x 4 nodes). Gather phase: lane = (head h, slot):
// holds agg[h][slot*16..+16] fp32; per edge reads 32 B of the 256-B xb row
// (8-fold lane duplication across head groups -> one row fetch). Normalized
// agg (x 1/8l) written bf16 to LDS in MFMA A-frag layout (XOR swizzle on the
// node index). Projection: out[16x32] = agg[16x1024] @ Wstack[1024x32],
// 64 MFMAs; B-frags linear from L2-resident Wstack.
__global__ __launch_bounds__(256) void aggregate_proj(
    const ushort_t* __restrict__ xb,
    const ushort_t* __restrict__ Wstack,
    const float* __restrict__ a_src8,
    const float* __restrict__ a_dst8,
    const int* __restrict__ deg,
    const ushort_t* __restrict__ ell,
    const float* __restrict__ bias,
    float* __restrict__ out, int N)
{
    __shared__ uint4 aggl[2048];          // 32 KB: [li(128)][nd(16)] 16-B slots, swizzled
    const int tid = threadIdx.x;
    const int w = tid >> 6;
    const int lane = tid & 63;
    const int h = lane >> 3;
    const int slot = lane & 7;
    const int bid16 = blockIdx.x * 16;

    for (int it = 0; it < 4; ++it) {
        const int nd = w * 4 + it;
        const int n = bid16 + nd;
        if (n < N) {
            float acc[16] = {0,0,0,0,0,0,0,0,0,0,0,0,0,0,0,0};
            float adh = a_dst8[(size_t)n * 8 + h];
            float l;
            {   // self loop
                float e = a_src8[(size_t)n * 8 + h] + adh;
                e = fmaxf(e, NEG_SLOPE * e);
                float p = __expf(e);
                uint4 g0 = *(const uint4*)&xb[(size_t)n * IN_DIM + slot * 16];
                uint4 g1 = *(const uint4*)&xb[(size_t)n * IN_DIM + slot * 16 + 8];
                fmab(g0, g1, p, acc);
                l = p;
            }
            int dn = deg[n]; if (dn > ELL_CAP) dn = ELL_CAP;
            const ushort_t* row = &ell[(size_t)n * ELL_CAP];
            for (int k = 0; k < dn; k += 4) {
                int s[4]; float av[4]; uint4 g0[4], g1[4]; bool m[4];
#pragma unroll
                for (int j = 0; j < 4; j++) {
                    m[j] = (k + j) < dn;
                    s[j] = (int)row[m[j] ? (k + j) : k];
                }
#pragma unroll
                for (int j = 0; j < 4; j++) av[j] = a_src8[(size_t)s[j] * 8 + h];
#pragma unroll
                for (int j = 0; j < 4; j++) {
                    g0[j] = *(const uint4*)&xb[(size_t)s[j] * IN_DIM + slot * 16];
                    g1[j] = *(const uint4*)&xb[(size_t)s[j] * IN_DIM + slot * 16 + 8];
                }
#pragma unroll
                for (int j = 0; j < 4; j++) {
                    float e = av[j] + adh;
                    e = fmaxf(e, NEG_SLOPE * e);
                    float p = m[j] ? __expf(e) : 0.f;
                    fmab(g0[j], g1[j], p, acc);
                    l += p;
                }
            }
            float sc = 0.125f / l;        // head-mean folded into normalize
            uint4 w0, w1;
            w0.x = pkbf(acc[0] * sc,  acc[1] * sc);
            w0.y = pkbf(acc[2] * sc,  acc[3] * sc);
            w0.z = pkbf(acc[4] * sc,  acc[5] * sc);
            w0.w = pkbf(acc[6] * sc,  acc[7] * sc);
            w1.x = pkbf(acc[8] * sc,  acc[9] * sc);
            w1.y = pkbf(acc[10] * sc, acc[11] * sc);
            w1.z = pkbf(acc[12] * sc, acc[13] * sc);
            w1.w = pkbf(acc[14] * sc, acc[15] * sc);
            int li0 = h * 16 + slot * 2;  // k-group hk>>3
            aggl[li0 * 16 + (nd ^ (li0 & 15))] = w0;
            int li1 = li0 + 1;
            aggl[li1 * 16 + (nd ^ (li1 & 15))] = w1;
        }
    }
    __syncthreads();

    // ---- projection: D[node][c] = sum_k agg[node][k] * Wstack[c][k] ----
    const int m15 = lane & 15, quad = lane >> 4;
    floatx4 o0 = {0.f, 0.f, 0.f, 0.f}, o1 = {0.f, 0.f, 0.f, 0.f};
    const ushort_t* aggus = (const ushort_t*)aggl;
#pragma unroll 4
    for (int ks = 0; ks < 32; ++ks) {
        int li = ks * 4 + quad;
        bf16x8 af = *(const bf16x8*)&aggus[(li * 16 + (m15 ^ (li & 15))) * 8];
        bf16x8 b0 = *(const bf16x8*)&Wstack[(size_t)m15 * 1024 + ks * 32 + quad * 8];
        bf16x8 b1 = *(const bf16x8*)&Wstack[(size_t)(16 + m15) * 1024 + ks * 32 + quad * 8];
        o0 = __builtin_amdgcn_mfma_f32_16x16x32_bf16(af, b0, o0, 0, 0, 0);
        o1 = __builtin_amdgcn_mfma_f32_16x16x32_bf16(af, b1, o1, 0, 0, 0);
    }
    float bv0 = bias[m15];
    float bv1 = bias[16 + m15];
#pragma unroll
    for (int reg = 0; reg < 4; ++reg) {
        int node = quad * 4 + reg;        // D row = A row = node
        int n = bid16 + node;
        if (n < N) {
            out[(size_t)n * OUT_DIM + m15]      = o0[reg] + bv0;
            out[(size_t)n * OUT_DIM + 16 + m15] = o1[reg] + bv1;
        }
    }
}

// ---------------- launch ----------------
extern "C" void kernel_launch(void* const* d_in, const int* in_sizes, int n_in,
                              void* d_out, int out_size, void* d_ws, size_t ws_size,
                              hipStream_t stream) {
    const float* x       = (const float*)d_in[0];
    const int*   eidx    = (const int*)d_in[1];
    const float* W       = (const float*)d_in[3];
    const float* att_src = (const float*)d_in[4];
    const float* att_dst = (const float*)d_in[5];
    const float* bias    = (const float*)d_in[6];
    float* out = (float*)d_out;

    const int N = in_sizes[0] / IN_DIM;
    const int E = in_sizes[1] / 2;
    const int* esrc = eidx;
    const int* edst = eidx + E;

    char* wsb = (char*)d_ws;
    size_t off = 0;
    auto alloc = [&](size_t bytes) -> void* {
        void* p = wsb + off;
        off = (off + bytes + 255) & ~(size_t)255;
        return p;
    };
    ushort_t* xb     = (ushort_t*)alloc((size_t)N * IN_DIM * 2);        // 12.8 MB
    ushort_t* Wstack = (ushort_t*)alloc((size_t)OUT_DIM * HEADS * IN_DIM * 2); // 64 KB
    float*    a_src8 = (float*)alloc((size_t)N * HEADS * 4);
    float*    a_dst8 = (float*)alloc((size_t)N * HEADS * 4);
    int*      deg    = (int*)alloc((size_t)N * 4);
    ushort_t* ell    = (ushort_t*)alloc((size_t)N * ELL_CAP * 2);

    const int npack = (N + 63) / 64;
    const int edge_blocks = (E / 4 + 255) / 256;

    hipMemsetAsync(deg, 0, (size_t)N * 4, stream);
    hipLaunchKernelGGL(prep_pack_build, dim3(16 + npack + edge_blocks), dim3(256), 0, stream,
                       x, W, att_src, att_dst, Wstack, xb, a_src8, a_dst8,
                       esrc, edst, deg, ell, N, E, npack);
    hipLaunchKernelGGL(aggregate_proj, dim3((N + 15) / 16), dim3(256), 0, stream,
                       xb, Wstack, a_src8, a_dst8, deg, ell, bias, out, N);
}

// Round 8
// 213.000 us; speedup vs baseline: 1.9231x; 1.9231x over previous
//
#include <hip/hip_runtime.h>
#include <hip/hip_bf16.h>

#define IN_DIM 128
#define HC 256
#define HEADS 8
#define OUT_DIM 32
#define NEG_SLOPE 0.2f
#define ELL_CAP 64           // Poisson(16) degrees: P(deg>63) ~ 1e-19 per node
#define DEG_STRIDE 32        // one deg counter per 128-B line: 16x fewer atomic hits/line

typedef unsigned short ushort_t;
typedef unsigned int uint_t;
typedef __attribute__((ext_vector_type(8))) short bf16x8;
typedef __attribute__((ext_vector_type(8))) unsigned short ushort8_t;
typedef __attribute__((ext_vector_type(4))) float floatx4;

__device__ inline float bf2f(ushort_t u) {
    return __uint_as_float(((uint_t)u) << 16);
}
// packed 2xf32 -> 2xbf16 (v_cvt_pk_bf16_f32), RNE
__device__ inline uint_t pkbf(float a, float b) {
    __hip_bfloat162 t = __float22bfloat162_rn(make_float2(a, b));
    union { __hip_bfloat162 h; uint_t u; } c;
    c.h = t;
    return c.u;
}

// ---------------- K1: fused [prep_w blocks | ELL-build blocks] ----------------
__global__ __launch_bounds__(256) void prep_build(const float* __restrict__ W,
                                                  ushort_t* __restrict__ Wf,
                                                  const int* __restrict__ esrc,
                                                  const int* __restrict__ edst,
                                                  int* __restrict__ deg,
                                                  ushort_t* __restrict__ ell, int E) {
    const int bid = blockIdx.x;
    const int tid = threadIdx.x;
    if (bid < 16) {
        int t = bid * 256 + tid;                 // 0..4095
        int lane = t & 63;
        int ks = (t >> 6) & 3;
        int nt = t >> 8;
        int n = nt * 16 + (lane & 15);
        int k0 = ks * 32 + (lane >> 4) * 8;
        float v[8];
#pragma unroll
        for (int j = 0; j < 8; j++) v[j] = W[(size_t)(k0 + j) * HC + n];
        uint4 pk;
        pk.x = pkbf(v[0], v[1]);
        pk.y = pkbf(v[2], v[3]);
        pk.z = pkbf(v[4], v[5]);
        pk.w = pkbf(v[6], v[7]);
        *(uint4*)&Wf[(size_t)t * 8] = pk;
        return;
    }
    int i = (bid - 16) * 256 + tid;
    int base = i * 4;
    if (base + 3 < E) {
        int4 d = *(const int4*)&edst[base];
        int4 s = *(const int4*)&esrc[base];
        int r0 = atomicAdd(&deg[(size_t)d.x * DEG_STRIDE], 1);
        int r1 = atomicAdd(&deg[(size_t)d.y * DEG_STRIDE], 1);
        int r2 = atomicAdd(&deg[(size_t)d.z * DEG_STRIDE], 1);
        int r3 = atomicAdd(&deg[(size_t)d.w * DEG_STRIDE], 1);
        if (r0 < ELL_CAP) ell[d.x * ELL_CAP + r0] = (ushort_t)s.x;
        if (r1 < ELL_CAP) ell[d.y * ELL_CAP + r1] = (ushort_t)s.y;
        if (r2 < ELL_CAP) ell[d.z * ELL_CAP + r2] = (ushort_t)s.z;
        if (r3 < ELL_CAP) ell[d.w * ELL_CAP + r3] = (ushort_t)s.w;
    } else {
        for (int j = base; j < E; j++) {
            int r = atomicAdd(&deg[(size_t)edst[j] * DEG_STRIDE], 1);
            if (r < ELL_CAP) ell[edst[j] * ELL_CAP + r] = (ushort_t)esrc[j];
        }
    }
}

// ---------------- K2: h2 = bf16(x @ W) via MFMA, operand-swapped ----------------
__global__ __launch_bounds__(256) void gemm_mfma(const float* __restrict__ x,
                                                 const ushort_t* __restrict__ Wf,
                                                 const float* __restrict__ att_s,
                                                 const float* __restrict__ att_d,
                                                 ushort_t* __restrict__ h2,
                                                 float* __restrict__ a_src,
                                                 float* __restrict__ a_dst, int N) {
    __shared__ ushort_t xs[128 * 136];
    const int tid = threadIdx.x;
    const int row0 = blockIdx.x * 128;
#pragma unroll
    for (int i = 0; i < 16; i++) {
        int slot = tid + i * 256;                // 4096 float4-slots
        int r = slot >> 5, kq = slot & 31;
        int gr = row0 + r;
        float4 v = (gr < N) ? *(const float4*)&x[(size_t)gr * IN_DIM + kq * 4]
                            : make_float4(0.f, 0.f, 0.f, 0.f);
        uint2 pk;
        pk.x = pkbf(v.x, v.y);
        pk.y = pkbf(v.z, v.w);
        *(uint2*)&xs[r * 136 + kq * 4] = pk;
    }
    __syncthreads();

    const int lane = tid & 63;
    const int w = tid >> 6;
    const int wrow = (w & 1) * 64;               // wave row offset
    const int wcol = (w >> 1) * 64;              // wave col offset within 128
    const int m15 = lane & 15, quad = lane >> 4;

#pragma unroll
    for (int ch = 0; ch < 2; ch++) {
        const int colblk = wcol + ch * 128;      // global col base (HC=256)
        floatx4 acc[4][4] = {};                  // [ct][rt]
#pragma unroll
        for (int ks = 0; ks < 4; ks++) {
            bf16x8 xb[4], wa[4];
#pragma unroll
            for (int rt = 0; rt < 4; rt++)
                xb[rt] = *(const bf16x8*)&xs[(wrow + rt * 16 + m15) * 136 + ks * 32 + quad * 8];
#pragma unroll
            for (int ct = 0; ct < 4; ct++) {
                int mtg = (colblk >> 4) + ct;
                wa[ct] = *(const bf16x8*)&Wf[(size_t)(((mtg * 4 + ks) * 64) + lane) * 8];
            }
#pragma unroll
            for (int ct = 0; ct < 4; ct++)
#pragma unroll
                for (int rt = 0; rt < 4; rt++)
                    acc[ct][rt] = __builtin_amdgcn_mfma_f32_16x16x32_bf16(wa[ct], xb[rt], acc[ct][rt], 0, 0, 0);
        }

        const int hb = colblk >> 5;              // heads hb, hb+1 in this 64-col span
        float asc[4][4], adc[4][4];
#pragma unroll
        for (int ct = 0; ct < 4; ct++)
#pragma unroll
            for (int reg = 0; reg < 4; reg++) {
                asc[ct][reg] = att_s[colblk + ct * 16 + quad * 4 + reg];
                adc[ct][reg] = att_d[colblk + ct * 16 + quad * 4 + reg];
            }
#pragma unroll
        for (int rt = 0; rt < 4; rt++) {
            int gr = row0 + wrow + rt * 16 + m15;
            bool ok = (gr < N);
            if (ok) {
#pragma unroll
                for (int ct = 0; ct < 4; ct++) {
                    uint2 pk;
                    pk.x = pkbf(acc[ct][rt][0], acc[ct][rt][1]);
                    pk.y = pkbf(acc[ct][rt][2], acc[ct][rt][3]);
                    *(uint2*)&h2[(size_t)gr * HC + colblk + ct * 16 + quad * 4] = pk;
                }
            }
            float sA = 0.f, sB = 0.f, dA = 0.f, dB = 0.f;
#pragma unroll
            for (int reg = 0; reg < 4; reg++) {
                sA += acc[0][rt][reg] * asc[0][reg] + acc[1][rt][reg] * asc[1][reg];
                sB += acc[2][rt][reg] * asc[2][reg] + acc[3][rt][reg] * asc[3][reg];
                dA += acc[0][rt][reg] * adc[0][reg] + acc[1][rt][reg] * adc[1][reg];
                dB += acc[2][rt][reg] * adc[2][reg] + acc[3][rt][reg] * adc[3][reg];
            }
            sA += __shfl_xor(sA, 16, 64); sA += __shfl_xor(sA, 32, 64);
            sB += __shfl_xor(sB, 16, 64); sB += __shfl_xor(sB, 32, 64);
            dA += __shfl_xor(dA, 16, 64); dA += __shfl_xor(dA, 32, 64);
            dB += __shfl_xor(dB, 16, 64); dB += __shfl_xor(dB, 32, 64);
            if (ok && quad == 0) {
                a_src[gr * HEADS + hb]     = sA;
                a_src[gr * HEADS + hb + 1] = sB;
                a_dst[gr * HEADS + hb]     = dA;
                a_dst[gr * HEADS + hb + 1] = dB;
            }
        }
    }
}

// ---------------- K3: aggregate — one wave per node, 2 edges per load step ----------------
__global__ __launch_bounds__(256) void aggregate(const ushort_t* __restrict__ h2,
                                                 const float* __restrict__ a_src,
                                                 const float* __restrict__ a_dst,
                                                 const int* __restrict__ deg,
                                                 const ushort_t* __restrict__ ell,
                                                 const float* __restrict__ bias,
                                                 float* __restrict__ out, int N) {
    int wave = threadIdx.x >> 6;
    int lane = threadIdx.x & 63;
    int n = blockIdx.x * 4 + wave;
    if (n >= N) return;
    int half = lane >> 5;
    int sl = lane & 31;
    int head = sl >> 2;
    int rowoff = sl * 8;                          // ushort offset into 256-elem row

    float adst = a_dst[n * HEADS + head];
    float e = a_src[n * HEADS + head] + adst;
    e = fmaxf(e, NEG_SLOPE * e);
    float p = (half == 0) ? __expf(e) : 0.f;
    ushort8_t hv = *(const ushort8_t*)&h2[(size_t)n * HC + rowoff];
    float acc[8];
#pragma unroll
    for (int j = 0; j < 8; j++) acc[j] = p * bf2f(hv[j]);
    float l = p;

    int dn = __builtin_amdgcn_readfirstlane(deg[(size_t)n * DEG_STRIDE]);
    if (dn > ELL_CAP) dn = ELL_CAP;
    const ushort_t* row = &ell[(size_t)n * ELL_CAP];
    int k = 0;
    for (; k + 7 < dn; k += 8) {                  // 4 pairs = 8 edges per iter
        int sidx[4];
        float ev[4];
        ushort8_t g[4];
#pragma unroll
        for (int j = 0; j < 4; j++) sidx[j] = (int)row[k + 2 * j + half];
#pragma unroll
        for (int j = 0; j < 4; j++) {
            g[j] = *(const ushort8_t*)&h2[(size_t)sidx[j] * HC + rowoff];
            ev[j] = a_src[sidx[j] * HEADS + head];
        }
#pragma unroll
        for (int j = 0; j < 4; j++) {
            float ej = ev[j] + adst;
            ej = fmaxf(ej, NEG_SLOPE * ej);
            float pj = __expf(ej);
#pragma unroll
            for (int c = 0; c < 8; c++) acc[c] += pj * bf2f(g[j][c]);
            l += pj;
        }
    }
    for (; k + 1 < dn; k += 2) {                  // pair loop
        int s0 = (int)row[k + half];
        float e0 = a_src[s0 * HEADS + head] + adst;
        ushort8_t g0 = *(const ushort8_t*)&h2[(size_t)s0 * HC + rowoff];
        e0 = fmaxf(e0, NEG_SLOPE * e0);
        float p0 = __expf(e0);
#pragma unroll
        for (int c = 0; c < 8; c++) acc[c] += p0 * bf2f(g0[c]);
        l += p0;
    }
    if (k < dn) {                                 // odd tail: half 0 only
        int s0 = (int)row[k];
        float e0 = a_src[s0 * HEADS + head] + adst;
        ushort8_t g0 = *(const ushort8_t*)&h2[(size_t)s0 * HC + rowoff];
        e0 = fmaxf(e0, NEG_SLOPE * e0);
        float p0 = (half == 0) ? __expf(e0) : 0.f;
#pragma unroll
        for (int c = 0; c < 8; c++) acc[c] += p0 * bf2f(g0[c]);
        l += p0;
    }

#pragma unroll
    for (int j = 0; j < 8; j++) acc[j] += __shfl_xor(acc[j], 32, 64);
    l += __shfl_xor(l, 32, 64);

    float inv = 0.125f / l;                       // fold head-mean 1/8 into normalize
#pragma unroll
    for (int j = 0; j < 8; j++) acc[j] *= inv;
#pragma unroll
    for (int off = 4; off < 32; off <<= 1)
#pragma unroll
        for (int j = 0; j < 8; j++) acc[j] += __shfl_xor(acc[j], off, 64);

    if (lane < 4) {                               // half 0, head 0
        int c8 = sl * 8;
        float4 b0 = *(const float4*)&bias[c8];
        float4 b1 = *(const float4*)&bias[c8 + 4];
        float4 o0 = make_float4(acc[0] + b0.x, acc[1] + b0.y, acc[2] + b0.z, acc[3] + b0.w);
        float4 o1 = make_float4(acc[4] + b1.x, acc[5] + b1.y, acc[6] + b1.z, acc[7] + b1.w);
        *(float4*)&out[(size_t)n * OUT_DIM + c8] = o0;
        *(float4*)&out[(size_t)n * OUT_DIM + c8 + 4] = o1;
    }
}

// ---------------- launch ----------------
extern "C" void kernel_launch(void* const* d_in, const int* in_sizes, int n_in,
                              void* d_out, int out_size, void* d_ws, size_t ws_size,
                              hipStream_t stream) {
    const float* x       = (const float*)d_in[0];
    const int*   eidx    = (const int*)d_in[1];
    const float* W       = (const float*)d_in[3];
    const float* att_src = (const float*)d_in[4];
    const float* att_dst = (const float*)d_in[5];
    const float* bias    = (const float*)d_in[6];
    float* out = (float*)d_out;

    const int N = in_sizes[0] / IN_DIM;
    const int E = in_sizes[1] / 2;
    const int* esrc = eidx;
    const int* edst = eidx + E;

    char* wsb = (char*)d_ws;
    size_t off = 0;
    auto alloc = [&](size_t bytes) -> void* {
        void* p = wsb + off;
        off = (off + bytes + 255) & ~(size_t)255;
        return p;
    };
    ushort_t* h2   = (ushort_t*)alloc((size_t)N * HC * 2);
    ushort_t* Wf   = (ushort_t*)alloc((size_t)IN_DIM * HC * 2);
    float*    a_src= (float*)alloc((size_t)N * HEADS * 4);
    float*    a_dst= (float*)alloc((size_t)N * HEADS * 4);
    int*      deg  = (int*)alloc((size_t)N * DEG_STRIDE * 4);   // padded: 1 counter / 128-B line
    ushort_t* ell  = (ushort_t*)alloc((size_t)N * ELL_CAP * 2);

    const int edge_blocks = (E / 4 + 255) / 256;

    hipMemsetAsync(deg, 0, (size_t)N * DEG_STRIDE * 4, stream);
    hipLaunchKernelGGL(prep_build, dim3(16 + edge_blocks), dim3(256), 0, stream,
                       W, Wf, esrc, edst, deg, ell, E);
    hipLaunchKernelGGL(gemm_mfma, dim3((N + 127) / 128), dim3(256), 0, stream,
                       x, Wf, att_src, att_dst, h2, a_src, a_dst, N);
    hipLaunchKernelGGL(aggregate, dim3((N + 3) / 4), dim3(256), 0, stream,
                       h2, a_src, a_dst, deg, ell, bias, out, N);
}